// Round 1
// baseline (48.733 us; speedup 1.0000x reference)
//
#include <hip/hip_runtime.h>

#define PERSONS 256
#define ROW 45   // 15 joints * 3 dims
#define KJ 15

__global__ __launch_bounds__(256) void limb_kernel(const float* __restrict__ in,
                                                   float* __restrict__ out, int B) {
    __shared__ float lds[PERSONS * ROW];  // 46,080 B
    const int tid = threadIdx.x;
    const long long bstart = (long long)blockIdx.x * PERSONS;
    const int npersons = (int)min((long long)PERSONS, (long long)B - bstart);
    const long long fbase = bstart * ROW;

    // ---- coalesced global -> LDS staging (float4) ----
    const int F  = npersons * ROW;
    const int Fv = F >> 2;                 // float4 count
    const float4* __restrict__ src4 = (const float4*)(in + fbase);
    float4* lds4 = (float4*)lds;
    for (int idx = tid; idx < Fv; idx += 256) lds4[idx] = src4[idx];
    for (int idx = (Fv << 2) + tid; idx < F; idx += 256) lds[idx] = in[fbase + idx];
    __syncthreads();

    // ---- per-person compute from LDS (lane stride 45: conflict-free) ----
    float r[KJ];
    const int conn[KJ] = {0, 0, 1, 1, 1, 3, 4, 5, 6, 2, 2, 9, 10, 11, 12};
    if (tid < npersons) {
        const float* s = &lds[tid * ROW];
        #pragma unroll
        for (int k = 0; k < KJ; ++k) {
            const int c = conn[k];
            const float dx = s[k * 3 + 0] - s[c * 3 + 0];
            const float dy = s[k * 3 + 1] - s[c * 3 + 1];
            const float dz = s[k * 3 + 2] - s[c * 3 + 2];
            r[k] = sqrtf(dx * dx + dy * dy + dz * dz);
        }
    }
    __syncthreads();  // all LDS reads done before reuse as output staging

    // ---- stage results in LDS (stride 15: conflict-free), then coalesced store ----
    if (tid < npersons) {
        #pragma unroll
        for (int k = 0; k < KJ; ++k) lds[tid * KJ + k] = r[k];
    }
    __syncthreads();

    const int G  = npersons * KJ;
    const int Gv = G >> 2;
    float4* __restrict__ dst4 = (float4*)(out + bstart * KJ);
    const float4* lds4c = (const float4*)lds;
    for (int idx = tid; idx < Gv; idx += 256) dst4[idx] = lds4c[idx];
    for (int idx = (Gv << 2) + tid; idx < G; idx += 256) out[bstart * KJ + idx] = lds[idx];
}

extern "C" void kernel_launch(void* const* d_in, const int* in_sizes, int n_in,
                              void* d_out, int out_size, void* d_ws, size_t ws_size,
                              hipStream_t stream) {
    const float* in = (const float*)d_in[0];
    float* out = (float*)d_out;
    const int B = in_sizes[0] / ROW;           // 1,000,000
    const int grid = (B + PERSONS - 1) / PERSONS;
    limb_kernel<<<grid, 256, 0, stream>>>(in, out, B);
}